// Round 29
// baseline (289.867 us; speedup 1.0000x reference)
//
#include <hip/hip_runtime.h>
#include <cstddef>
#include <cstdint>
#include <math.h>

typedef __bf16 bf16_t;
typedef __bf16 bf16x8 __attribute__((ext_vector_type(8)));
typedef float  f32x4  __attribute__((ext_vector_type(4)));

#define MFMA16(A,B,C) __builtin_amdgcn_mfma_f32_16x16x32_bf16((A),(B),(C),0,0,0)
#define QFIX_CAP 262144
#define QWIN 2e-3f   // flag window (t-units) = 10 sigma of 1-pass GEMM error

// B=2, L=2048, D=1024, H=16, Dh=64.
// r29 = r28 + qfix occupancy: 32-d chunks -> LDS 16.9KB/block -> 9 blocks/CU
// (was 33KB -> 4).  Chunks 0-15 -> r0 (d 0..511 ascending), 16-31 -> r1;
// merge fadd_rn -> bit-identical to r11 chain -> absmax invariant 0.0390625.

__device__ __forceinline__ void gload16(const bf16_t* g, bf16_t* l)
{
    auto* lp = reinterpret_cast<__attribute__((address_space(3))) uint32_t*>(
                   reinterpret_cast<uintptr_t>(l));
    const auto* gp = reinterpret_cast<const __attribute__((address_space(1))) uint32_t*>(
                   reinterpret_cast<uintptr_t>(g));
    __builtin_amdgcn_global_load_lds(gp, lp, 16, 0, 0);
}

// ---------------------------------------------------------------------------
__global__ void k_conv_x(const float* __restrict__ x, bf16_t* __restrict__ xhi)
{
    int i = blockIdx.x * blockDim.x + threadIdx.x;
    float4 v = reinterpret_cast<const float4*>(x)[i];
    bf16_t* ph = xhi + 4*(size_t)i;
    ph[0]=(bf16_t)v.x; ph[1]=(bf16_t)v.y; ph[2]=(bf16_t)v.z; ph[3]=(bf16_t)v.w;
}

// W f32 [k][n] (1024x1024) -> T[n][k] bf16
__global__ void k_transpose(const float* __restrict__ W, bf16_t* __restrict__ T)
{
    __shared__ float tile[32][33];
    int t = threadIdx.x, r = t >> 5, c = t & 31;
    int k0 = blockIdx.y * 32, n0 = blockIdx.x * 32;
#pragma unroll
    for (int i = 0; i < 4; i++)
        tile[r + i*8][c] = W[(size_t)(k0 + r + i*8) * 1024 + n0 + c];
    __syncthreads();
#pragma unroll
    for (int i = 0; i < 4; i++) {
        int nr = r + i*8;
        T[(size_t)(n0 + nr) * 1024 + k0 + c] = (bf16_t)tile[c][nr];
    }
}

// W f32 [k][n] -> T f32 [n][k]  (for the exact qfix row reads)
__global__ void k_transpose_f32(const float* __restrict__ W, float* __restrict__ T)
{
    __shared__ float tile[32][33];
    int t = threadIdx.x, r = t >> 5, c = t & 31;
    int k0 = blockIdx.y * 32, n0 = blockIdx.x * 32;
#pragma unroll
    for (int i = 0; i < 4; i++)
        tile[r + i*8][c] = W[(size_t)(k0 + r + i*8) * 1024 + n0 + c];
    __syncthreads();
#pragma unroll
    for (int i = 0; i < 4; i++) {
        int nr = r + i*8;
        T[(size_t)(n0 + nr) * 1024 + k0 + c] = tile[c][nr];
    }
}

// ---------------------------------------------------------------------------
// Single-pass bf16 MFMA GEMM, depth-2 prefetch, 3 LDS buffers, XCD-local B.
// MODE 0 (QKV): 128x128 tile, N=3072. Epilogue: Q floor+flag(QWIN) / K / V^T.
// MODE 1 (out-proj): 64x128 tile, N=1024 -> f32 d_out + bo.
template<int MODE>
__launch_bounds__(256)
__global__ void k_gemm3(const bf16_t* __restrict__ A, const bf16_t* __restrict__ Bt,
                        const float* __restrict__ b0, const float* __restrict__ b1,
                        const float* __restrict__ b2,
                        bf16_t* __restrict__ qout, int2* __restrict__ qwl,
                        int* __restrict__ qcnt,
                        bf16_t* __restrict__ kho, bf16_t* __restrict__ vho,
                        float* __restrict__ fout)
{
    constexpr int BM = (MODE == 0) ? 128 : 64;
    __shared__ bf16_t As[3][BM*32]  __attribute__((aligned(16)));
    __shared__ bf16_t Bs[3][128*32] __attribute__((aligned(16)));

    const int bid = blockIdx.x;
    const int xcd = bid & 7;
    const int i   = bid >> 3;
    int n0, m0;
    if constexpr (MODE == 0) {
        n0 = (xcd * 3 + (i % 3)) * 128;   // each XCD owns 3 n-tiles (L2-resident B)
        m0 = (i / 3) * 128;
    } else {
        n0 = xcd * 128;
        m0 = i * 64;
    }

    const int tid = threadIdx.x;
    const int wid = tid >> 6, lane = tid & 63, lane16 = lane & 15, lg = lane >> 4;
    constexpr int WM = (MODE == 0) ? 64 : 32;
    const int wm = (wid >> 1) * WM, wn = (wid & 1) * 64;
    constexpr int MI = (MODE == 0) ? 4 : 2;

    f32x4 acc[MI][4] = {};

    auto STAGE = [&](int buf, int kt) {
        const int k0 = kt * 32;
#pragma unroll
        for (int i2 = 0; i2 < BM/64; i2++) {
            const int c = tid + i2*256;
            const int row = c >> 2, col = (c & 3) * 8;
            gload16(&A[(size_t)(m0 + row) * 1024 + k0 + col], &As[buf][c*8]);
        }
#pragma unroll
        for (int i2 = 0; i2 < 2; i2++) {
            const int c = tid + i2*256;
            const int row = c >> 2, col = (c & 3) * 8;
            gload16(&Bt[(size_t)(n0 + row) * 1024 + k0 + col], &Bs[buf][c*8]);
        }
    };

    STAGE(0, 0);
    STAGE(1, 1);
    for (int kt = 0; kt < 32; ++kt) {
        const int cur = kt % 3;
        if (kt < 31) {
            if constexpr (MODE == 0) { asm volatile("s_waitcnt vmcnt(4)" ::: "memory"); }
            else                     { asm volatile("s_waitcnt vmcnt(3)" ::: "memory"); }
        } else asm volatile("s_waitcnt vmcnt(0)" ::: "memory");
        __builtin_amdgcn_s_barrier();

        bf16x8 a[MI], b[4];
#pragma unroll
        for (int ii = 0; ii < MI; ii++)
            a[ii] = *reinterpret_cast<const bf16x8*>(&As[cur][(wm + ii*16 + lane16)*32 + lg*8]);
#pragma unroll
        for (int j = 0; j < 4; j++)
            b[j] = *reinterpret_cast<const bf16x8*>(&Bs[cur][(wn + j*16 + lane16)*32 + lg*8]);
#pragma unroll
        for (int ii = 0; ii < MI; ii++)
#pragma unroll
            for (int j = 0; j < 4; j++)
                acc[ii][j] = MFMA16(a[ii], b[j], acc[ii][j]);

        if (kt + 2 < 32) STAGE((kt + 2) % 3, kt + 2);
    }

    if constexpr (MODE == 1) {
#pragma unroll
        for (int j = 0; j < 4; j++) {
            const int n = n0 + wn + j*16 + lane16;
#pragma unroll
            for (int ii = 0; ii < MI; ii++)
#pragma unroll
                for (int r = 0; r < 4; r++) {
                    const int m = m0 + wm + ii*16 + lg*4 + r;
                    fout[(size_t)m*1024 + n] = acc[ii][j][r] + b0[n];
                }
        }
    } else if (n0 >= 1024) {
#pragma unroll
        for (int j = 0; j < 4; j++) {
            const int n = n0 + wn + j*16 + lane16;
#pragma unroll
            for (int ii = 0; ii < MI; ii++)
#pragma unroll
                for (int r = 0; r < 4; r++) {
                    const int m = m0 + wm + ii*16 + lg*4 + r;
                    const int bb = m >> 11, l = m & 2047;
                    float v = acc[ii][j][r];
                    if (n < 2048) {
                        const int nk = n - 1024;
                        kho[(((size_t)(bb*16 + (nk>>6)))*2048 + l)*64 + (nk&63)] =
                            (bf16_t)(v + b1[nk]);
                    } else {
                        const int nv = n - 2048;
                        vho[(((size_t)(bb*16 + (nv>>6)))*64 + (nv&63))*2048 + l] =
                            (bf16_t)(v + b2[nv]);
                    }
                }
        }
    } else {
        // Q epilogue: floors + wave-aggregated flag append (1 atomic/wave)
        int cnt = 0;
#pragma unroll
        for (int j = 0; j < 4; j++) {
            const int n = n0 + wn + j*16 + lane16;
            const float bias = b0[n];
#pragma unroll
            for (int ii = 0; ii < MI; ii++)
#pragma unroll
                for (int r = 0; r < 4; r++) {
                    const int m = m0 + wm + ii*16 + lg*4 + r;
                    const int bb = m >> 11, l = m & 2047;
                    float t  = (acc[ii][j][r] + bias) * 0.125f;
                    float fl = floorf(t);
                    float fr = t - fl;
                    cnt += (fr < QWIN || fr > 1.0f - QWIN) ? 1 : 0;
                    qout[(((size_t)(bb*16 + (n>>6)))*2048 + l)*64 + (n&63)] = (bf16_t)fl;
                }
        }
        int pre = cnt;
#pragma unroll
        for (int off = 1; off < 64; off <<= 1) {
            int t2 = __shfl_up(pre, off);
            if (lane >= off) pre += t2;
        }
        int total = __shfl(pre, 63);
        int base = 0;
        if (lane == 63 && total > 0) base = atomicAdd(qcnt, total);
        base = __shfl(base, 63);
        int idx = base + pre - cnt;
#pragma unroll
        for (int j = 0; j < 4; j++) {
            const int n = n0 + wn + j*16 + lane16;
            const float bias = b0[n];
#pragma unroll
            for (int ii = 0; ii < MI; ii++)
#pragma unroll
                for (int r = 0; r < 4; r++) {
                    const int m = m0 + wm + ii*16 + lg*4 + r;
                    float t  = (acc[ii][j][r] + bias) * 0.125f;
                    float fr = t - floorf(t);
                    if (fr < QWIN || fr > 1.0f - QWIN) {
                        if (idx < QFIX_CAP) qwl[idx] = make_int2(m, n);
                        idx++;
                    }
                }
        }
    }
}

// ---------------------------------------------------------------------------
// Wave-cooperative exact fixup: 1 wave per 64 elements; 32-d chunks
// (LDS 16.9KB -> 9 blocks/CU).  Chunks 0-15 -> r0, 16-31 -> r1, merge
// fadd_rn: bit-identical to r11 chain.
__launch_bounds__(64)
__global__ void k_qfix(const float* __restrict__ x, const float* __restrict__ WqT,
                       const float* __restrict__ bq, const int2* __restrict__ wl,
                       const int* __restrict__ count, bf16_t* __restrict__ qout)
{
    __shared__ float xs [64][33];
    __shared__ float wsd[64][33];
    int cnt = *count; if (cnt > QFIX_CAP) cnt = QFIX_CAP;
    const int base = blockIdx.x * 64;
    if (base >= cnt) return;
    const int lane = threadIdx.x;
    const int i = base + lane;
    const bool act = (i < cnt);
    const int2 e = wl[act ? i : base];
    const int m = e.x, n = e.y;
    const int half = lane >> 5;      // 0/1: which of 2 rows this lane stages
    const int dloc = lane & 31;

    float r0 = 0.f, r1 = 0.f;
#pragma unroll 1
    for (int c = 0; c < 32; ++c) {
        const int d0 = c * 32;
#pragma unroll 8
        for (int s2 = 0; s2 < 32; ++s2) {
            const int s = s2 * 2 + half;
            int ms = __shfl(m, s);
            int ns = __shfl(n, s);
            xs [s][dloc] = x  [(size_t)ms * 1024 + d0 + dloc];   // coalesced 128B
            wsd[s][dloc] = WqT[(size_t)ns * 1024 + d0 + dloc];   // coalesced 128B
        }
        __syncthreads();
        float racc = (c < 16) ? r0 : r1;
#pragma unroll
        for (int d = 0; d < 32; ++d)
            racc = fmaf(xs[lane][d], wsd[lane][d], racc);        // ascending-d chain
        if (c < 16) r0 = racc; else r1 = racc;
        __syncthreads();
    }
    if (act) {
        float acc = __fadd_rn(r0, r1);                           // KC=512 block merge
        float q = floorf(__fmul_rn(__fadd_rn(acc, bq[n]), 0.125f));
        qout[(((size_t)((m>>11)*16 + (n>>6)))*2048 + (m&2047))*64 + (n&63)] = (bf16_t)q;
    }
}

// ---------------------------------------------------------------------------
// Flash attention, bf16 K/V/P.  grid (16, B*H); block x handles q-tiles
// {x, 31-x}.  T14 pipeline: double-buffered K/V, reg-issue one tile ahead,
// ds_write after compute; 1 barrier/tile.  T13 skip-rescale (bit-identical).
// T5 setprio around MFMA.
__launch_bounds__(256)
__global__ void k_attn(const bf16_t* __restrict__ qf,
                       const bf16_t* __restrict__ khi,
                       const bf16_t* __restrict__ vhiT,
                       bf16_t* __restrict__ ohi)
{
    __shared__ bf16_t Kh[2][64*72] __attribute__((aligned(16)));
    __shared__ bf16_t Vh[2][64*72] __attribute__((aligned(16)));
    __shared__ bf16_t Ph[4*16*72]  __attribute__((aligned(16)));
    const int tid = threadIdx.x, wid = tid >> 6, lane = tid & 63;
    const int lane16 = lane & 15, lg = lane >> 4;
    const int bx = blockIdx.x, bh = blockIdx.y;
    const bf16_t* qb  = qf   + (size_t)bh * 2048 * 64;
    const bf16_t* khb = khi  + (size_t)bh * 2048 * 64;
    const bf16_t* vhb = vhiT + (size_t)bh * 64 * 2048;
    const int b = bh >> 4, h = bh & 15;
    const float L2E = 1.44269504088896f;

    bf16x8 kreg[2], vreg[2];
    auto ISSUE = [&](int t) {
        const int kv0 = t * 64;
#pragma unroll
        for (int i = 0; i < 2; i++) {
            int cc = tid + i*256, row = cc >> 3, col8 = (cc & 7) * 8;
            kreg[i] = *reinterpret_cast<const bf16x8*>(&khb[(size_t)(kv0+row)*64 + col8]);
            vreg[i] = *reinterpret_cast<const bf16x8*>(&vhb[(size_t)row*2048 + kv0 + col8]);
        }
    };
    auto WRITE = [&](int buf) {
#pragma unroll
        for (int i = 0; i < 2; i++) {
            int cc = tid + i*256, row = cc >> 3, col8 = (cc & 7) * 8;
            *reinterpret_cast<bf16x8*>(&Kh[buf][row*72 + col8]) = kreg[i];
            *reinterpret_cast<bf16x8*>(&Vh[buf][row*72 + col8]) = vreg[i];
        }
    };

#pragma unroll 1
    for (int pass = 0; pass < 2; pass++) {
        const int qt = pass ? (31 - bx) : bx;
        const int q0 = qt * 64;
        const int qrow16 = q0 + wid*16 + lane16;

        bf16x8 qfr0 = *reinterpret_cast<const bf16x8*>(&qb[(size_t)qrow16*64 + lg*8]);
        bf16x8 qfr1 = *reinterpret_cast<const bf16x8*>(&qb[(size_t)qrow16*64 + 32 + lg*8]);

        f32x4 acco[4] = {};
        float mrow[4] = {-1e30f, -1e30f, -1e30f, -1e30f};
        float lrow[4] = {0.f, 0.f, 0.f, 0.f};

        __syncthreads();            // prior pass readers done before buf0 reuse
        ISSUE(0);
        WRITE(0);

        for (int t = 0; t <= qt; t++) {
            const int cur = t & 1;
            if (t < qt) ISSUE(t + 1);      // in flight during compute
            __syncthreads();               // buf[cur] visible; old buf free

            f32x4 s[4] = {};
            __builtin_amdgcn_s_setprio(1);
#pragma unroll
            for (int st = 0; st < 4; st++) {
                const int ro = (st*16 + lane16)*72;
                bf16x8 kh0 = *reinterpret_cast<const bf16x8*>(&Kh[cur][ro + lg*8]);
                bf16x8 kh1 = *reinterpret_cast<const bf16x8*>(&Kh[cur][ro + 32 + lg*8]);
                s[st] = MFMA16(qfr0, kh0, s[st]);
                s[st] = MFMA16(qfr1, kh1, s[st]);
            }
            __builtin_amdgcn_s_setprio(0);
            if (t == qt) {
#pragma unroll
                for (int st = 0; st < 4; st++) {
                    int key = t*64 + st*16 + lane16;
#pragma unroll
                    for (int r = 0; r < 4; r++) {
                        int qr = q0 + wid*16 + lg*4 + r;
                        if (key > qr) s[st][r] = -1e30f;
                    }
                }
            }
            float rmax[4];
#pragma unroll
            for (int r = 0; r < 4; r++)
                rmax[r] = fmaxf(fmaxf(s[0][r], s[1][r]), fmaxf(s[2][r], s[3][r]));
#pragma unroll
            for (int off = 1; off < 16; off <<= 1)
#pragma unroll
                for (int r = 0; r < 4; r++) rmax[r] = fmaxf(rmax[r], __shfl_xor(rmax[r], off));

            bool grow = (rmax[0] > mrow[0]) || (rmax[1] > mrow[1]) ||
                        (rmax[2] > mrow[2]) || (rmax[3] > mrow[3]);
            float scl[4] = {1.f, 1.f, 1.f, 1.f};
            const bool doscale = __any(grow);
            if (doscale) {
#pragma unroll
                for (int r = 0; r < 4; r++) {
                    float mn = fmaxf(mrow[r], rmax[r]);
                    scl[r] = exp2f((mrow[r] - mn) * L2E);
                    mrow[r] = mn;
                }
            }
            float rs[4] = {0.f, 0.f, 0.f, 0.f};
#pragma unroll
            for (int st = 0; st < 4; st++) {
#pragma unroll
                for (int r = 0; r < 4; r++) {
                    float p = exp2f((s[st][r] - mrow[r]) * L2E);
                    rs[r] += p;
                    Ph[wid*16*72 + (lg*4 + r)*72 + st*16 + lane16] = (bf16_t)p;
                }
            }
#pragma unroll
            for (int off = 1; off < 16; off <<= 1)
#pragma unroll
                for (int r = 0; r < 4; r++) rs[r] += __shfl_xor(rs[r], off);
            if (doscale) {
#pragma unroll
                for (int r = 0; r < 4; r++) lrow[r] = lrow[r]*scl[r] + rs[r];
#pragma unroll
                for (int nf = 0; nf < 4; nf++)
#pragma unroll
                    for (int r = 0; r < 4; r++) acco[nf][r] *= scl[r];
            } else {
#pragma unroll
                for (int r = 0; r < 4; r++) lrow[r] += rs[r];
            }

            __builtin_amdgcn_s_setprio(1);
#pragma unroll
            for (int ks = 0; ks < 2; ks++) {
                bf16x8 phf = *reinterpret_cast<const bf16x8*>(&Ph[wid*16*72 + lane16*72 + ks*32 + lg*8]);
#pragma unroll
                for (int nf = 0; nf < 4; nf++) {
                    bf16x8 vh = *reinterpret_cast<const bf16x8*>(&Vh[cur][(nf*16 + lane16)*72 + ks*32 + lg*8]);
                    acco[nf] = MFMA16(phf, vh, acco[nf]);
                }
            }
            __builtin_amdgcn_s_setprio(0);

            if (t < qt) WRITE(cur ^ 1);    // stage next tile (loads landed by now)
        }

#pragma unroll
        for (int r = 0; r < 4; r++) {
            float inv = 1.0f / lrow[r];
            int qr = q0 + wid*16 + lg*4 + r;
            size_t base = ((size_t)(b*2048 + qr))*1024 + h*64;
#pragma unroll
            for (int nf = 0; nf < 4; nf++)
                ohi[base + nf*16 + lane16] = (bf16_t)(acco[nf][r] * inv);
        }
    }
}

// ---------------------------------------------------------------------------
extern "C" void kernel_launch(void* const* d_in, const int* in_sizes, int n_in,
                              void* d_out, int out_size, void* d_ws, size_t ws_size,
                              hipStream_t stream)
{
    const float* x  = (const float*)d_in[0];
    const float* Wq = (const float*)d_in[1];
    const float* bq = (const float*)d_in[2];
    const float* Wk = (const float*)d_in[3];
    const float* bk = (const float*)d_in[4];
    const float* Wv = (const float*)d_in[5];
    const float* bv = (const float*)d_in[6];
    const float* Wo = (const float*)d_in[7];
    const float* bo = (const float*)d_in[8];

    char* ws = (char*)d_ws;
    const size_t MB = (size_t)1 << 20;
    bf16_t* xhi    = (bf16_t*)(ws +  0*MB);  // [4096][1024] 8MB
    bf16_t* WThi   = (bf16_t*)(ws +  8*MB);  // [3072][1024] 6MB (Wq|Wk|Wv ^T)
    bf16_t* WoThi  = (bf16_t*)(ws + 14*MB);  // 2MB
    bf16_t* qbuf   = (bf16_t*)(ws + 16*MB);  // [B,H,L,Dh] 8MB
    bf16_t* khibuf = (bf16_t*)(ws + 24*MB);  // 8MB
    bf16_t* vhiT   = (bf16_t*)(ws + 32*MB);  // [B,H,Dh,L] 8MB
    bf16_t* ohibuf = (bf16_t*)(ws + 40*MB);  // [4096][1024] 8MB
    int2*   qwl    = (int2*)  (ws + 48*MB);  // 2MB
    int*    qcnt   = (int*)   (ws + 50*MB);  // 4B
    float*  WqTf   = (float*) (ws + 52*MB);  // [1024][1024] f32 4MB (qfix rows)

    hipMemsetAsync(qcnt, 0, 4, stream);
    k_conv_x<<<4096, 256, 0, stream>>>(x, xhi);
    dim3 tg(32, 32);
    k_transpose<<<tg, 256, 0, stream>>>(Wq, WThi);
    k_transpose<<<tg, 256, 0, stream>>>(Wk, WThi + (size_t)1024*1024);
    k_transpose<<<tg, 256, 0, stream>>>(Wv, WThi + (size_t)2048*1024);
    k_transpose<<<tg, 256, 0, stream>>>(Wo, WoThi);
    k_transpose_f32<<<tg, 256, 0, stream>>>(Wq, WqTf);

    k_gemm3<0><<<768, 256, 0, stream>>>(xhi, WThi, bq, bk, bv,
                                        qbuf, qwl, qcnt, khibuf, vhiT, nullptr);
    k_qfix<<<4096, 64, 0, stream>>>(x, WqTf, bq, qwl, qcnt, qbuf);
    k_attn<<<dim3(16, 32), 256, 0, stream>>>(qbuf, khibuf, vhiT, ohibuf);
    k_gemm3<1><<<512, 256, 0, stream>>>(ohibuf, WoThi, bo, nullptr, nullptr,
                                        nullptr, nullptr, nullptr,
                                        nullptr, nullptr, (float*)d_out);
}

// Round 30
// 259.539 us; speedup vs baseline: 1.1169x; 1.1169x over previous
//
#include <hip/hip_runtime.h>
#include <cstddef>
#include <cstdint>
#include <math.h>

typedef __bf16 bf16_t;
typedef __bf16 bf16x8 __attribute__((ext_vector_type(8)));
typedef float  f32x4  __attribute__((ext_vector_type(4)));

#define MFMA16(A,B,C) __builtin_amdgcn_mfma_f32_16x16x32_bf16((A),(B),(C),0,0,0)
#define QFIX_CAP 262144
#define QWIN 2e-3f   // flag window (t-units) = 10 sigma of 1-pass GEMM error

// B=2, L=2048, D=1024, H=16, Dh=64.
// r30 = r28 + async-DMA qfix staging: per 64-d chunk, 128 global_load_lds(4B)
// DMAs (wave-uniform row base + lane*4; rows padded to 65 floats -> 2-way-free
// banks), one vmcnt(0), then per-lane serial chains from LDS.  Single-wave
// blocks: no barriers; lgkmcnt(0) guards WAR.  Chain order bit-identical to
// r11 -> absmax invariant 0.0390625.

__device__ __forceinline__ void gload16(const bf16_t* g, bf16_t* l)
{
    auto* lp = reinterpret_cast<__attribute__((address_space(3))) uint32_t*>(
                   reinterpret_cast<uintptr_t>(l));
    const auto* gp = reinterpret_cast<const __attribute__((address_space(1))) uint32_t*>(
                   reinterpret_cast<uintptr_t>(g));
    __builtin_amdgcn_global_load_lds(gp, lp, 16, 0, 0);
}

__device__ __forceinline__ void gload4(const float* g, float* l)
{
    auto* lp = reinterpret_cast<__attribute__((address_space(3))) uint32_t*>(
                   reinterpret_cast<uintptr_t>(l));
    const auto* gp = reinterpret_cast<const __attribute__((address_space(1))) uint32_t*>(
                   reinterpret_cast<uintptr_t>(g));
    __builtin_amdgcn_global_load_lds(gp, lp, 4, 0, 0);
}

// ---------------------------------------------------------------------------
__global__ void k_conv_x(const float* __restrict__ x, bf16_t* __restrict__ xhi)
{
    int i = blockIdx.x * blockDim.x + threadIdx.x;
    float4 v = reinterpret_cast<const float4*>(x)[i];
    bf16_t* ph = xhi + 4*(size_t)i;
    ph[0]=(bf16_t)v.x; ph[1]=(bf16_t)v.y; ph[2]=(bf16_t)v.z; ph[3]=(bf16_t)v.w;
}

// W f32 [k][n] (1024x1024) -> T[n][k] bf16
__global__ void k_transpose(const float* __restrict__ W, bf16_t* __restrict__ T)
{
    __shared__ float tile[32][33];
    int t = threadIdx.x, r = t >> 5, c = t & 31;
    int k0 = blockIdx.y * 32, n0 = blockIdx.x * 32;
#pragma unroll
    for (int i = 0; i < 4; i++)
        tile[r + i*8][c] = W[(size_t)(k0 + r + i*8) * 1024 + n0 + c];
    __syncthreads();
#pragma unroll
    for (int i = 0; i < 4; i++) {
        int nr = r + i*8;
        T[(size_t)(n0 + nr) * 1024 + k0 + c] = (bf16_t)tile[c][nr];
    }
}

// W f32 [k][n] -> T f32 [n][k]  (for the exact qfix row reads)
__global__ void k_transpose_f32(const float* __restrict__ W, float* __restrict__ T)
{
    __shared__ float tile[32][33];
    int t = threadIdx.x, r = t >> 5, c = t & 31;
    int k0 = blockIdx.y * 32, n0 = blockIdx.x * 32;
#pragma unroll
    for (int i = 0; i < 4; i++)
        tile[r + i*8][c] = W[(size_t)(k0 + r + i*8) * 1024 + n0 + c];
    __syncthreads();
#pragma unroll
    for (int i = 0; i < 4; i++) {
        int nr = r + i*8;
        T[(size_t)(n0 + nr) * 1024 + k0 + c] = tile[c][nr];
    }
}

// ---------------------------------------------------------------------------
// Single-pass bf16 MFMA GEMM, depth-2 prefetch, 3 LDS buffers, XCD-local B.
// MODE 0 (QKV): 128x128 tile, N=3072. Epilogue: Q floor+flag(QWIN) / K / V^T.
// MODE 1 (out-proj): 64x128 tile, N=1024 -> f32 d_out + bo.
template<int MODE>
__launch_bounds__(256)
__global__ void k_gemm3(const bf16_t* __restrict__ A, const bf16_t* __restrict__ Bt,
                        const float* __restrict__ b0, const float* __restrict__ b1,
                        const float* __restrict__ b2,
                        bf16_t* __restrict__ qout, int2* __restrict__ qwl,
                        int* __restrict__ qcnt,
                        bf16_t* __restrict__ kho, bf16_t* __restrict__ vho,
                        float* __restrict__ fout)
{
    constexpr int BM = (MODE == 0) ? 128 : 64;
    __shared__ bf16_t As[3][BM*32]  __attribute__((aligned(16)));
    __shared__ bf16_t Bs[3][128*32] __attribute__((aligned(16)));

    const int bid = blockIdx.x;
    const int xcd = bid & 7;
    const int i   = bid >> 3;
    int n0, m0;
    if constexpr (MODE == 0) {
        n0 = (xcd * 3 + (i % 3)) * 128;   // each XCD owns 3 n-tiles (L2-resident B)
        m0 = (i / 3) * 128;
    } else {
        n0 = xcd * 128;
        m0 = i * 64;
    }

    const int tid = threadIdx.x;
    const int wid = tid >> 6, lane = tid & 63, lane16 = lane & 15, lg = lane >> 4;
    constexpr int WM = (MODE == 0) ? 64 : 32;
    const int wm = (wid >> 1) * WM, wn = (wid & 1) * 64;
    constexpr int MI = (MODE == 0) ? 4 : 2;

    f32x4 acc[MI][4] = {};

    auto STAGE = [&](int buf, int kt) {
        const int k0 = kt * 32;
#pragma unroll
        for (int i2 = 0; i2 < BM/64; i2++) {
            const int c = tid + i2*256;
            const int row = c >> 2, col = (c & 3) * 8;
            gload16(&A[(size_t)(m0 + row) * 1024 + k0 + col], &As[buf][c*8]);
        }
#pragma unroll
        for (int i2 = 0; i2 < 2; i2++) {
            const int c = tid + i2*256;
            const int row = c >> 2, col = (c & 3) * 8;
            gload16(&Bt[(size_t)(n0 + row) * 1024 + k0 + col], &Bs[buf][c*8]);
        }
    };

    STAGE(0, 0);
    STAGE(1, 1);
    for (int kt = 0; kt < 32; ++kt) {
        const int cur = kt % 3;
        if (kt < 31) {
            if constexpr (MODE == 0) { asm volatile("s_waitcnt vmcnt(4)" ::: "memory"); }
            else                     { asm volatile("s_waitcnt vmcnt(3)" ::: "memory"); }
        } else asm volatile("s_waitcnt vmcnt(0)" ::: "memory");
        __builtin_amdgcn_s_barrier();

        bf16x8 a[MI], b[4];
#pragma unroll
        for (int ii = 0; ii < MI; ii++)
            a[ii] = *reinterpret_cast<const bf16x8*>(&As[cur][(wm + ii*16 + lane16)*32 + lg*8]);
#pragma unroll
        for (int j = 0; j < 4; j++)
            b[j] = *reinterpret_cast<const bf16x8*>(&Bs[cur][(wn + j*16 + lane16)*32 + lg*8]);
#pragma unroll
        for (int ii = 0; ii < MI; ii++)
#pragma unroll
            for (int j = 0; j < 4; j++)
                acc[ii][j] = MFMA16(a[ii], b[j], acc[ii][j]);

        if (kt + 2 < 32) STAGE((kt + 2) % 3, kt + 2);
    }

    if constexpr (MODE == 1) {
#pragma unroll
        for (int j = 0; j < 4; j++) {
            const int n = n0 + wn + j*16 + lane16;
#pragma unroll
            for (int ii = 0; ii < MI; ii++)
#pragma unroll
                for (int r = 0; r < 4; r++) {
                    const int m = m0 + wm + ii*16 + lg*4 + r;
                    fout[(size_t)m*1024 + n] = acc[ii][j][r] + b0[n];
                }
        }
    } else if (n0 >= 1024) {
#pragma unroll
        for (int j = 0; j < 4; j++) {
            const int n = n0 + wn + j*16 + lane16;
#pragma unroll
            for (int ii = 0; ii < MI; ii++)
#pragma unroll
                for (int r = 0; r < 4; r++) {
                    const int m = m0 + wm + ii*16 + lg*4 + r;
                    const int bb = m >> 11, l = m & 2047;
                    float v = acc[ii][j][r];
                    if (n < 2048) {
                        const int nk = n - 1024;
                        kho[(((size_t)(bb*16 + (nk>>6)))*2048 + l)*64 + (nk&63)] =
                            (bf16_t)(v + b1[nk]);
                    } else {
                        const int nv = n - 2048;
                        vho[(((size_t)(bb*16 + (nv>>6)))*64 + (nv&63))*2048 + l] =
                            (bf16_t)(v + b2[nv]);
                    }
                }
        }
    } else {
        // Q epilogue: floors + wave-aggregated flag append (1 atomic/wave)
        int cnt = 0;
#pragma unroll
        for (int j = 0; j < 4; j++) {
            const int n = n0 + wn + j*16 + lane16;
            const float bias = b0[n];
#pragma unroll
            for (int ii = 0; ii < MI; ii++)
#pragma unroll
                for (int r = 0; r < 4; r++) {
                    const int m = m0 + wm + ii*16 + lg*4 + r;
                    const int bb = m >> 11, l = m & 2047;
                    float t  = (acc[ii][j][r] + bias) * 0.125f;
                    float fl = floorf(t);
                    float fr = t - fl;
                    cnt += (fr < QWIN || fr > 1.0f - QWIN) ? 1 : 0;
                    qout[(((size_t)(bb*16 + (n>>6)))*2048 + l)*64 + (n&63)] = (bf16_t)fl;
                }
        }
        int pre = cnt;
#pragma unroll
        for (int off = 1; off < 64; off <<= 1) {
            int t2 = __shfl_up(pre, off);
            if (lane >= off) pre += t2;
        }
        int total = __shfl(pre, 63);
        int base = 0;
        if (lane == 63 && total > 0) base = atomicAdd(qcnt, total);
        base = __shfl(base, 63);
        int idx = base + pre - cnt;
#pragma unroll
        for (int j = 0; j < 4; j++) {
            const int n = n0 + wn + j*16 + lane16;
            const float bias = b0[n];
#pragma unroll
            for (int ii = 0; ii < MI; ii++)
#pragma unroll
                for (int r = 0; r < 4; r++) {
                    const int m = m0 + wm + ii*16 + lg*4 + r;
                    float t  = (acc[ii][j][r] + bias) * 0.125f;
                    float fr = t - floorf(t);
                    if (fr < QWIN || fr > 1.0f - QWIN) {
                        if (idx < QFIX_CAP) qwl[idx] = make_int2(m, n);
                        idx++;
                    }
                }
        }
    }
}

// ---------------------------------------------------------------------------
// Wave-cooperative exact fixup, async-DMA staged: 1 wave per 64 elements.
// Per 64-d chunk: 128 global_load_lds(4B) DMAs (row s -> xs[s][0..63],
// uniform base + lane*4), one vmcnt(0), per-lane serial chains from LDS.
// Rows padded to 65 floats: read bank = (lane+d)%32, 2-way = free.
// Chunks 0-7 -> r0, 8-15 -> r1; merge fadd_rn: bit-identical to r11.
__launch_bounds__(64)
__global__ void k_qfix(const float* __restrict__ x, const float* __restrict__ WqT,
                       const float* __restrict__ bq, const int2* __restrict__ wl,
                       const int* __restrict__ count, bf16_t* __restrict__ qout)
{
    __shared__ float xs [64][65];
    __shared__ float wsd[64][65];
    int cnt = *count; if (cnt > QFIX_CAP) cnt = QFIX_CAP;
    const int base = blockIdx.x * 64;
    if (base >= cnt) return;
    const int lane = threadIdx.x;
    const int i = base + lane;
    const bool act = (i < cnt);
    const int2 e = wl[act ? i : base];
    const int m = e.x, n = e.y;

    float r0 = 0.f, r1 = 0.f;
#pragma unroll 1
    for (int c = 0; c < 16; ++c) {
        const int d0 = c * 64;
#pragma unroll 8
        for (int s = 0; s < 64; ++s) {
            int ms = __shfl(m, s);
            int ns = __shfl(n, s);
            gload4(&x  [(size_t)ms * 1024 + d0 + lane], &xs [s][0]);   // DMA, 256B row
            gload4(&WqT[(size_t)ns * 1024 + d0 + lane], &wsd[s][0]);   // DMA, 256B row
        }
        asm volatile("s_waitcnt vmcnt(0)" ::: "memory");   // all DMAs landed
        float racc = (c < 8) ? r0 : r1;
#pragma unroll
        for (int d = 0; d < 64; ++d)
            racc = fmaf(xs[lane][d], wsd[lane][d], racc);  // ascending-d chain
        if (c < 8) r0 = racc; else r1 = racc;
        asm volatile("s_waitcnt lgkmcnt(0)" ::: "memory"); // reads done before next DMA (WAR)
    }
    if (act) {
        float acc = __fadd_rn(r0, r1);                     // KC=512 block merge
        float q = floorf(__fmul_rn(__fadd_rn(acc, bq[n]), 0.125f));
        qout[(((size_t)((m>>11)*16 + (n>>6)))*2048 + (m&2047))*64 + (n&63)] = (bf16_t)q;
    }
}

// ---------------------------------------------------------------------------
// Flash attention, bf16 K/V/P.  grid (16, B*H); block x handles q-tiles
// {x, 31-x}.  T14 pipeline: double-buffered K/V, reg-issue one tile ahead,
// ds_write after compute; 1 barrier/tile.  T13 skip-rescale (bit-identical).
// T5 setprio around MFMA.
__launch_bounds__(256)
__global__ void k_attn(const bf16_t* __restrict__ qf,
                       const bf16_t* __restrict__ khi,
                       const bf16_t* __restrict__ vhiT,
                       bf16_t* __restrict__ ohi)
{
    __shared__ bf16_t Kh[2][64*72] __attribute__((aligned(16)));
    __shared__ bf16_t Vh[2][64*72] __attribute__((aligned(16)));
    __shared__ bf16_t Ph[4*16*72]  __attribute__((aligned(16)));
    const int tid = threadIdx.x, wid = tid >> 6, lane = tid & 63;
    const int lane16 = lane & 15, lg = lane >> 4;
    const int bx = blockIdx.x, bh = blockIdx.y;
    const bf16_t* qb  = qf   + (size_t)bh * 2048 * 64;
    const bf16_t* khb = khi  + (size_t)bh * 2048 * 64;
    const bf16_t* vhb = vhiT + (size_t)bh * 64 * 2048;
    const int b = bh >> 4, h = bh & 15;
    const float L2E = 1.44269504088896f;

    bf16x8 kreg[2], vreg[2];
    auto ISSUE = [&](int t) {
        const int kv0 = t * 64;
#pragma unroll
        for (int i = 0; i < 2; i++) {
            int cc = tid + i*256, row = cc >> 3, col8 = (cc & 7) * 8;
            kreg[i] = *reinterpret_cast<const bf16x8*>(&khb[(size_t)(kv0+row)*64 + col8]);
            vreg[i] = *reinterpret_cast<const bf16x8*>(&vhb[(size_t)row*2048 + kv0 + col8]);
        }
    };
    auto WRITE = [&](int buf) {
#pragma unroll
        for (int i = 0; i < 2; i++) {
            int cc = tid + i*256, row = cc >> 3, col8 = (cc & 7) * 8;
            *reinterpret_cast<bf16x8*>(&Kh[buf][row*72 + col8]) = kreg[i];
            *reinterpret_cast<bf16x8*>(&Vh[buf][row*72 + col8]) = vreg[i];
        }
    };

#pragma unroll 1
    for (int pass = 0; pass < 2; pass++) {
        const int qt = pass ? (31 - bx) : bx;
        const int q0 = qt * 64;
        const int qrow16 = q0 + wid*16 + lane16;

        bf16x8 qfr0 = *reinterpret_cast<const bf16x8*>(&qb[(size_t)qrow16*64 + lg*8]);
        bf16x8 qfr1 = *reinterpret_cast<const bf16x8*>(&qb[(size_t)qrow16*64 + 32 + lg*8]);

        f32x4 acco[4] = {};
        float mrow[4] = {-1e30f, -1e30f, -1e30f, -1e30f};
        float lrow[4] = {0.f, 0.f, 0.f, 0.f};

        __syncthreads();            // prior pass readers done before buf0 reuse
        ISSUE(0);
        WRITE(0);

        for (int t = 0; t <= qt; t++) {
            const int cur = t & 1;
            if (t < qt) ISSUE(t + 1);      // in flight during compute
            __syncthreads();               // buf[cur] visible; old buf free

            f32x4 s[4] = {};
            __builtin_amdgcn_s_setprio(1);
#pragma unroll
            for (int st = 0; st < 4; st++) {
                const int ro = (st*16 + lane16)*72;
                bf16x8 kh0 = *reinterpret_cast<const bf16x8*>(&Kh[cur][ro + lg*8]);
                bf16x8 kh1 = *reinterpret_cast<const bf16x8*>(&Kh[cur][ro + 32 + lg*8]);
                s[st] = MFMA16(qfr0, kh0, s[st]);
                s[st] = MFMA16(qfr1, kh1, s[st]);
            }
            __builtin_amdgcn_s_setprio(0);
            if (t == qt) {
#pragma unroll
                for (int st = 0; st < 4; st++) {
                    int key = t*64 + st*16 + lane16;
#pragma unroll
                    for (int r = 0; r < 4; r++) {
                        int qr = q0 + wid*16 + lg*4 + r;
                        if (key > qr) s[st][r] = -1e30f;
                    }
                }
            }
            float rmax[4];
#pragma unroll
            for (int r = 0; r < 4; r++)
                rmax[r] = fmaxf(fmaxf(s[0][r], s[1][r]), fmaxf(s[2][r], s[3][r]));
#pragma unroll
            for (int off = 1; off < 16; off <<= 1)
#pragma unroll
                for (int r = 0; r < 4; r++) rmax[r] = fmaxf(rmax[r], __shfl_xor(rmax[r], off));

            bool grow = (rmax[0] > mrow[0]) || (rmax[1] > mrow[1]) ||
                        (rmax[2] > mrow[2]) || (rmax[3] > mrow[3]);
            float scl[4] = {1.f, 1.f, 1.f, 1.f};
            const bool doscale = __any(grow);
            if (doscale) {
#pragma unroll
                for (int r = 0; r < 4; r++) {
                    float mn = fmaxf(mrow[r], rmax[r]);
                    scl[r] = exp2f((mrow[r] - mn) * L2E);
                    mrow[r] = mn;
                }
            }
            float rs[4] = {0.f, 0.f, 0.f, 0.f};
#pragma unroll
            for (int st = 0; st < 4; st++) {
#pragma unroll
                for (int r = 0; r < 4; r++) {
                    float p = exp2f((s[st][r] - mrow[r]) * L2E);
                    rs[r] += p;
                    Ph[wid*16*72 + (lg*4 + r)*72 + st*16 + lane16] = (bf16_t)p;
                }
            }
#pragma unroll
            for (int off = 1; off < 16; off <<= 1)
#pragma unroll
                for (int r = 0; r < 4; r++) rs[r] += __shfl_xor(rs[r], off);
            if (doscale) {
#pragma unroll
                for (int r = 0; r < 4; r++) lrow[r] = lrow[r]*scl[r] + rs[r];
#pragma unroll
                for (int nf = 0; nf < 4; nf++)
#pragma unroll
                    for (int r = 0; r < 4; r++) acco[nf][r] *= scl[r];
            } else {
#pragma unroll
                for (int r = 0; r < 4; r++) lrow[r] += rs[r];
            }

            __builtin_amdgcn_s_setprio(1);
#pragma unroll
            for (int ks = 0; ks < 2; ks++) {
                bf16x8 phf = *reinterpret_cast<const bf16x8*>(&Ph[wid*16*72 + lane16*72 + ks*32 + lg*8]);
#pragma unroll
                for (int nf = 0; nf < 4; nf++) {
                    bf16x8 vh = *reinterpret_cast<const bf16x8*>(&Vh[cur][(nf*16 + lane16)*72 + ks*32 + lg*8]);
                    acco[nf] = MFMA16(phf, vh, acco[nf]);
                }
            }
            __builtin_amdgcn_s_setprio(0);

            if (t < qt) WRITE(cur ^ 1);    // stage next tile (loads landed by now)
        }

#pragma unroll
        for (int r = 0; r < 4; r++) {
            float inv = 1.0f / lrow[r];
            int qr = q0 + wid*16 + lg*4 + r;
            size_t base = ((size_t)(b*2048 + qr))*1024 + h*64;
#pragma unroll
            for (int nf = 0; nf < 4; nf++)
                ohi[base + nf*16 + lane16] = (bf16_t)(acco[nf][r] * inv);
        }
    }
}

// ---------------------------------------------------------------------------
extern "C" void kernel_launch(void* const* d_in, const int* in_sizes, int n_in,
                              void* d_out, int out_size, void* d_ws, size_t ws_size,
                              hipStream_t stream)
{
    const float* x  = (const float*)d_in[0];
    const float* Wq = (const float*)d_in[1];
    const float* bq = (const float*)d_in[2];
    const float* Wk = (const float*)d_in[3];
    const float* bk = (const float*)d_in[4];
    const float* Wv = (const float*)d_in[5];
    const float* bv = (const float*)d_in[6];
    const float* Wo = (const float*)d_in[7];
    const float* bo = (const float*)d_in[8];

    char* ws = (char*)d_ws;
    const size_t MB = (size_t)1 << 20;
    bf16_t* xhi    = (bf16_t*)(ws +  0*MB);  // [4096][1024] 8MB
    bf16_t* WThi   = (bf16_t*)(ws +  8*MB);  // [3072][1024] 6MB (Wq|Wk|Wv ^T)
    bf16_t* WoThi  = (bf16_t*)(ws + 14*MB);  // 2MB
    bf16_t* qbuf   = (bf16_t*)(ws + 16*MB);  // [B,H,L,Dh] 8MB
    bf16_t* khibuf = (bf16_t*)(ws + 24*MB);  // 8MB
    bf16_t* vhiT   = (bf16_t*)(ws + 32*MB);  // [B,H,Dh,L] 8MB
    bf16_t* ohibuf = (bf16_t*)(ws + 40*MB);  // [4096][1024] 8MB
    int2*   qwl    = (int2*)  (ws + 48*MB);  // 2MB
    int*    qcnt   = (int*)   (ws + 50*MB);  // 4B
    float*  WqTf   = (float*) (ws + 52*MB);  // [1024][1024] f32 4MB (qfix rows)

    hipMemsetAsync(qcnt, 0, 4, stream);
    k_conv_x<<<4096, 256, 0, stream>>>(x, xhi);
    dim3 tg(32, 32);
    k_transpose<<<tg, 256, 0, stream>>>(Wq, WThi);
    k_transpose<<<tg, 256, 0, stream>>>(Wk, WThi + (size_t)1024*1024);
    k_transpose<<<tg, 256, 0, stream>>>(Wv, WThi + (size_t)2048*1024);
    k_transpose<<<tg, 256, 0, stream>>>(Wo, WoThi);
    k_transpose_f32<<<tg, 256, 0, stream>>>(Wq, WqTf);

    k_gemm3<0><<<768, 256, 0, stream>>>(xhi, WThi, bq, bk, bv,
                                        qbuf, qwl, qcnt, khibuf, vhiT, nullptr);
    k_qfix<<<4096, 64, 0, stream>>>(x, WqTf, bq, qwl, qcnt, qbuf);
    k_attn<<<dim3(16, 32), 256, 0, stream>>>(qbuf, khibuf, vhiT, ohibuf);
    k_gemm3<1><<<512, 256, 0, stream>>>(ohibuf, WoThi, bo, nullptr, nullptr,
                                        nullptr, nullptr, nullptr,
                                        nullptr, nullptr, (float*)d_out);
}

// Round 31
// 256.781 us; speedup vs baseline: 1.1288x; 1.0107x over previous
//
#include <hip/hip_runtime.h>
#include <cstddef>
#include <cstdint>
#include <math.h>

typedef __bf16 bf16_t;
typedef __bf16 bf16x8 __attribute__((ext_vector_type(8)));
typedef float  f32x4  __attribute__((ext_vector_type(4)));

#define MFMA16(A,B,C) __builtin_amdgcn_mfma_f32_16x16x32_bf16((A),(B),(C),0,0,0)
#define QFIX_CAP 262144
#define QWIN 2e-3f   // flag window (t-units) = 10 sigma of 1-pass GEMM error

// B=2, L=2048, D=1024, H=16, Dh=64.
// r31 = r30 + attention K/V L2 residency: flat grid 512, each XCD owns 4
// heads (bh = xcd*4 + i&3, bx = i>>2) -> per-XCD K/V working set 2MB < 4MB
// L2 -> K/V fetched from HBM once (~16MB vs 270MB demand).  Pure block
// permutation -> absmax invariant 0.0390625.

__device__ __forceinline__ void gload16(const bf16_t* g, bf16_t* l)
{
    auto* lp = reinterpret_cast<__attribute__((address_space(3))) uint32_t*>(
                   reinterpret_cast<uintptr_t>(l));
    const auto* gp = reinterpret_cast<const __attribute__((address_space(1))) uint32_t*>(
                   reinterpret_cast<uintptr_t>(g));
    __builtin_amdgcn_global_load_lds(gp, lp, 16, 0, 0);
}

__device__ __forceinline__ void gload4(const float* g, float* l)
{
    auto* lp = reinterpret_cast<__attribute__((address_space(3))) uint32_t*>(
                   reinterpret_cast<uintptr_t>(l));
    const auto* gp = reinterpret_cast<const __attribute__((address_space(1))) uint32_t*>(
                   reinterpret_cast<uintptr_t>(g));
    __builtin_amdgcn_global_load_lds(gp, lp, 4, 0, 0);
}

// ---------------------------------------------------------------------------
__global__ void k_conv_x(const float* __restrict__ x, bf16_t* __restrict__ xhi)
{
    int i = blockIdx.x * blockDim.x + threadIdx.x;
    float4 v = reinterpret_cast<const float4*>(x)[i];
    bf16_t* ph = xhi + 4*(size_t)i;
    ph[0]=(bf16_t)v.x; ph[1]=(bf16_t)v.y; ph[2]=(bf16_t)v.z; ph[3]=(bf16_t)v.w;
}

// W f32 [k][n] (1024x1024) -> T[n][k] bf16
__global__ void k_transpose(const float* __restrict__ W, bf16_t* __restrict__ T)
{
    __shared__ float tile[32][33];
    int t = threadIdx.x, r = t >> 5, c = t & 31;
    int k0 = blockIdx.y * 32, n0 = blockIdx.x * 32;
#pragma unroll
    for (int i = 0; i < 4; i++)
        tile[r + i*8][c] = W[(size_t)(k0 + r + i*8) * 1024 + n0 + c];
    __syncthreads();
#pragma unroll
    for (int i = 0; i < 4; i++) {
        int nr = r + i*8;
        T[(size_t)(n0 + nr) * 1024 + k0 + c] = (bf16_t)tile[c][nr];
    }
}

// W f32 [k][n] -> T f32 [n][k]  (for the exact qfix row reads)
__global__ void k_transpose_f32(const float* __restrict__ W, float* __restrict__ T)
{
    __shared__ float tile[32][33];
    int t = threadIdx.x, r = t >> 5, c = t & 31;
    int k0 = blockIdx.y * 32, n0 = blockIdx.x * 32;
#pragma unroll
    for (int i = 0; i < 4; i++)
        tile[r + i*8][c] = W[(size_t)(k0 + r + i*8) * 1024 + n0 + c];
    __syncthreads();
#pragma unroll
    for (int i = 0; i < 4; i++) {
        int nr = r + i*8;
        T[(size_t)(n0 + nr) * 1024 + k0 + c] = tile[c][nr];
    }
}

// ---------------------------------------------------------------------------
// Single-pass bf16 MFMA GEMM, depth-2 prefetch, 3 LDS buffers, XCD-local B.
// MODE 0 (QKV): 128x128 tile, N=3072. Epilogue: Q floor+flag(QWIN) / K / V^T.
// MODE 1 (out-proj): 64x128 tile, N=1024 -> f32 d_out + bo.
template<int MODE>
__launch_bounds__(256)
__global__ void k_gemm3(const bf16_t* __restrict__ A, const bf16_t* __restrict__ Bt,
                        const float* __restrict__ b0, const float* __restrict__ b1,
                        const float* __restrict__ b2,
                        bf16_t* __restrict__ qout, int2* __restrict__ qwl,
                        int* __restrict__ qcnt,
                        bf16_t* __restrict__ kho, bf16_t* __restrict__ vho,
                        float* __restrict__ fout)
{
    constexpr int BM = (MODE == 0) ? 128 : 64;
    __shared__ bf16_t As[3][BM*32]  __attribute__((aligned(16)));
    __shared__ bf16_t Bs[3][128*32] __attribute__((aligned(16)));

    const int bid = blockIdx.x;
    const int xcd = bid & 7;
    const int i   = bid >> 3;
    int n0, m0;
    if constexpr (MODE == 0) {
        n0 = (xcd * 3 + (i % 3)) * 128;   // each XCD owns 3 n-tiles (L2-resident B)
        m0 = (i / 3) * 128;
    } else {
        n0 = xcd * 128;
        m0 = i * 64;
    }

    const int tid = threadIdx.x;
    const int wid = tid >> 6, lane = tid & 63, lane16 = lane & 15, lg = lane >> 4;
    constexpr int WM = (MODE == 0) ? 64 : 32;
    const int wm = (wid >> 1) * WM, wn = (wid & 1) * 64;
    constexpr int MI = (MODE == 0) ? 4 : 2;

    f32x4 acc[MI][4] = {};

    auto STAGE = [&](int buf, int kt) {
        const int k0 = kt * 32;
#pragma unroll
        for (int i2 = 0; i2 < BM/64; i2++) {
            const int c = tid + i2*256;
            const int row = c >> 2, col = (c & 3) * 8;
            gload16(&A[(size_t)(m0 + row) * 1024 + k0 + col], &As[buf][c*8]);
        }
#pragma unroll
        for (int i2 = 0; i2 < 2; i2++) {
            const int c = tid + i2*256;
            const int row = c >> 2, col = (c & 3) * 8;
            gload16(&Bt[(size_t)(n0 + row) * 1024 + k0 + col], &Bs[buf][c*8]);
        }
    };

    STAGE(0, 0);
    STAGE(1, 1);
    for (int kt = 0; kt < 32; ++kt) {
        const int cur = kt % 3;
        if (kt < 31) {
            if constexpr (MODE == 0) { asm volatile("s_waitcnt vmcnt(4)" ::: "memory"); }
            else                     { asm volatile("s_waitcnt vmcnt(3)" ::: "memory"); }
        } else asm volatile("s_waitcnt vmcnt(0)" ::: "memory");
        __builtin_amdgcn_s_barrier();

        bf16x8 a[MI], b[4];
#pragma unroll
        for (int ii = 0; ii < MI; ii++)
            a[ii] = *reinterpret_cast<const bf16x8*>(&As[cur][(wm + ii*16 + lane16)*32 + lg*8]);
#pragma unroll
        for (int j = 0; j < 4; j++)
            b[j] = *reinterpret_cast<const bf16x8*>(&Bs[cur][(wn + j*16 + lane16)*32 + lg*8]);
#pragma unroll
        for (int ii = 0; ii < MI; ii++)
#pragma unroll
            for (int j = 0; j < 4; j++)
                acc[ii][j] = MFMA16(a[ii], b[j], acc[ii][j]);

        if (kt + 2 < 32) STAGE((kt + 2) % 3, kt + 2);
    }

    if constexpr (MODE == 1) {
#pragma unroll
        for (int j = 0; j < 4; j++) {
            const int n = n0 + wn + j*16 + lane16;
#pragma unroll
            for (int ii = 0; ii < MI; ii++)
#pragma unroll
                for (int r = 0; r < 4; r++) {
                    const int m = m0 + wm + ii*16 + lg*4 + r;
                    fout[(size_t)m*1024 + n] = acc[ii][j][r] + b0[n];
                }
        }
    } else if (n0 >= 1024) {
#pragma unroll
        for (int j = 0; j < 4; j++) {
            const int n = n0 + wn + j*16 + lane16;
#pragma unroll
            for (int ii = 0; ii < MI; ii++)
#pragma unroll
                for (int r = 0; r < 4; r++) {
                    const int m = m0 + wm + ii*16 + lg*4 + r;
                    const int bb = m >> 11, l = m & 2047;
                    float v = acc[ii][j][r];
                    if (n < 2048) {
                        const int nk = n - 1024;
                        kho[(((size_t)(bb*16 + (nk>>6)))*2048 + l)*64 + (nk&63)] =
                            (bf16_t)(v + b1[nk]);
                    } else {
                        const int nv = n - 2048;
                        vho[(((size_t)(bb*16 + (nv>>6)))*64 + (nv&63))*2048 + l] =
                            (bf16_t)(v + b2[nv]);
                    }
                }
        }
    } else {
        // Q epilogue: floors + wave-aggregated flag append (1 atomic/wave)
        int cnt = 0;
#pragma unroll
        for (int j = 0; j < 4; j++) {
            const int n = n0 + wn + j*16 + lane16;
            const float bias = b0[n];
#pragma unroll
            for (int ii = 0; ii < MI; ii++)
#pragma unroll
                for (int r = 0; r < 4; r++) {
                    const int m = m0 + wm + ii*16 + lg*4 + r;
                    const int bb = m >> 11, l = m & 2047;
                    float t  = (acc[ii][j][r] + bias) * 0.125f;
                    float fl = floorf(t);
                    float fr = t - fl;
                    cnt += (fr < QWIN || fr > 1.0f - QWIN) ? 1 : 0;
                    qout[(((size_t)(bb*16 + (n>>6)))*2048 + l)*64 + (n&63)] = (bf16_t)fl;
                }
        }
        int pre = cnt;
#pragma unroll
        for (int off = 1; off < 64; off <<= 1) {
            int t2 = __shfl_up(pre, off);
            if (lane >= off) pre += t2;
        }
        int total = __shfl(pre, 63);
        int base = 0;
        if (lane == 63 && total > 0) base = atomicAdd(qcnt, total);
        base = __shfl(base, 63);
        int idx = base + pre - cnt;
#pragma unroll
        for (int j = 0; j < 4; j++) {
            const int n = n0 + wn + j*16 + lane16;
            const float bias = b0[n];
#pragma unroll
            for (int ii = 0; ii < MI; ii++)
#pragma unroll
                for (int r = 0; r < 4; r++) {
                    const int m = m0 + wm + ii*16 + lg*4 + r;
                    float t  = (acc[ii][j][r] + bias) * 0.125f;
                    float fr = t - floorf(t);
                    if (fr < QWIN || fr > 1.0f - QWIN) {
                        if (idx < QFIX_CAP) qwl[idx] = make_int2(m, n);
                        idx++;
                    }
                }
        }
    }
}

// ---------------------------------------------------------------------------
// Wave-cooperative exact fixup, async-DMA staged: 1 wave per 64 elements.
__launch_bounds__(64)
__global__ void k_qfix(const float* __restrict__ x, const float* __restrict__ WqT,
                       const float* __restrict__ bq, const int2* __restrict__ wl,
                       const int* __restrict__ count, bf16_t* __restrict__ qout)
{
    __shared__ float xs [64][65];
    __shared__ float wsd[64][65];
    int cnt = *count; if (cnt > QFIX_CAP) cnt = QFIX_CAP;
    const int base = blockIdx.x * 64;
    if (base >= cnt) return;
    const int lane = threadIdx.x;
    const int i = base + lane;
    const bool act = (i < cnt);
    const int2 e = wl[act ? i : base];
    const int m = e.x, n = e.y;

    float r0 = 0.f, r1 = 0.f;
#pragma unroll 1
    for (int c = 0; c < 16; ++c) {
        const int d0 = c * 64;
#pragma unroll 8
        for (int s = 0; s < 64; ++s) {
            int ms = __shfl(m, s);
            int ns = __shfl(n, s);
            gload4(&x  [(size_t)ms * 1024 + d0 + lane], &xs [s][0]);   // DMA, 256B row
            gload4(&WqT[(size_t)ns * 1024 + d0 + lane], &wsd[s][0]);   // DMA, 256B row
        }
        asm volatile("s_waitcnt vmcnt(0)" ::: "memory");   // all DMAs landed
        float racc = (c < 8) ? r0 : r1;
#pragma unroll
        for (int d = 0; d < 64; ++d)
            racc = fmaf(xs[lane][d], wsd[lane][d], racc);  // ascending-d chain
        if (c < 8) r0 = racc; else r1 = racc;
        asm volatile("s_waitcnt lgkmcnt(0)" ::: "memory"); // reads done before next DMA (WAR)
    }
    if (act) {
        float acc = __fadd_rn(r0, r1);                     // KC=512 block merge
        float q = floorf(__fmul_rn(__fadd_rn(acc, bq[n]), 0.125f));
        qout[(((size_t)((m>>11)*16 + (n>>6)))*2048 + (m&2047))*64 + (n&63)] = (bf16_t)q;
    }
}

// ---------------------------------------------------------------------------
// Flash attention, bf16 K/V/P.  Flat grid 512: xcd = bid&7 owns 4 heads
// (bh = xcd*4 + (i&3)), bx = i>>2; block handles q-tiles {bx, 31-bx}.
// Per-XCD K/V working set 2MB -> L2-resident.  T14 pipeline, T13 skip-rescale,
// T5 setprio.
__launch_bounds__(256)
__global__ void k_attn(const bf16_t* __restrict__ qf,
                       const bf16_t* __restrict__ khi,
                       const bf16_t* __restrict__ vhiT,
                       bf16_t* __restrict__ ohi)
{
    __shared__ bf16_t Kh[2][64*72] __attribute__((aligned(16)));
    __shared__ bf16_t Vh[2][64*72] __attribute__((aligned(16)));
    __shared__ bf16_t Ph[4*16*72]  __attribute__((aligned(16)));
    const int tid = threadIdx.x, wid = tid >> 6, lane = tid & 63;
    const int lane16 = lane & 15, lg = lane >> 4;
    const int bid = blockIdx.x;
    const int xcd = bid & 7;
    const int ib  = bid >> 3;            // 0..63
    const int bh  = xcd * 4 + (ib & 3);  // 4 heads per XCD -> K/V L2-resident
    const int bx  = ib >> 2;             // 0..15
    const bf16_t* qb  = qf   + (size_t)bh * 2048 * 64;
    const bf16_t* khb = khi  + (size_t)bh * 2048 * 64;
    const bf16_t* vhb = vhiT + (size_t)bh * 64 * 2048;
    const int b = bh >> 4, h = bh & 15;
    const float L2E = 1.44269504088896f;

    bf16x8 kreg[2], vreg[2];
    auto ISSUE = [&](int t) {
        const int kv0 = t * 64;
#pragma unroll
        for (int i = 0; i < 2; i++) {
            int cc = tid + i*256, row = cc >> 3, col8 = (cc & 7) * 8;
            kreg[i] = *reinterpret_cast<const bf16x8*>(&khb[(size_t)(kv0+row)*64 + col8]);
            vreg[i] = *reinterpret_cast<const bf16x8*>(&vhb[(size_t)row*2048 + kv0 + col8]);
        }
    };
    auto WRITE = [&](int buf) {
#pragma unroll
        for (int i = 0; i < 2; i++) {
            int cc = tid + i*256, row = cc >> 3, col8 = (cc & 7) * 8;
            *reinterpret_cast<bf16x8*>(&Kh[buf][row*72 + col8]) = kreg[i];
            *reinterpret_cast<bf16x8*>(&Vh[buf][row*72 + col8]) = vreg[i];
        }
    };

#pragma unroll 1
    for (int pass = 0; pass < 2; pass++) {
        const int qt = pass ? (31 - bx) : bx;
        const int q0 = qt * 64;
        const int qrow16 = q0 + wid*16 + lane16;

        bf16x8 qfr0 = *reinterpret_cast<const bf16x8*>(&qb[(size_t)qrow16*64 + lg*8]);
        bf16x8 qfr1 = *reinterpret_cast<const bf16x8*>(&qb[(size_t)qrow16*64 + 32 + lg*8]);

        f32x4 acco[4] = {};
        float mrow[4] = {-1e30f, -1e30f, -1e30f, -1e30f};
        float lrow[4] = {0.f, 0.f, 0.f, 0.f};

        __syncthreads();            // prior pass readers done before buf0 reuse
        ISSUE(0);
        WRITE(0);

        for (int t = 0; t <= qt; t++) {
            const int cur = t & 1;
            if (t < qt) ISSUE(t + 1);      // in flight during compute
            __syncthreads();               // buf[cur] visible; old buf free

            f32x4 s[4] = {};
            __builtin_amdgcn_s_setprio(1);
#pragma unroll
            for (int st = 0; st < 4; st++) {
                const int ro = (st*16 + lane16)*72;
                bf16x8 kh0 = *reinterpret_cast<const bf16x8*>(&Kh[cur][ro + lg*8]);
                bf16x8 kh1 = *reinterpret_cast<const bf16x8*>(&Kh[cur][ro + 32 + lg*8]);
                s[st] = MFMA16(qfr0, kh0, s[st]);
                s[st] = MFMA16(qfr1, kh1, s[st]);
            }
            __builtin_amdgcn_s_setprio(0);
            if (t == qt) {
#pragma unroll
                for (int st = 0; st < 4; st++) {
                    int key = t*64 + st*16 + lane16;
#pragma unroll
                    for (int r = 0; r < 4; r++) {
                        int qr = q0 + wid*16 + lg*4 + r;
                        if (key > qr) s[st][r] = -1e30f;
                    }
                }
            }
            float rmax[4];
#pragma unroll
            for (int r = 0; r < 4; r++)
                rmax[r] = fmaxf(fmaxf(s[0][r], s[1][r]), fmaxf(s[2][r], s[3][r]));
#pragma unroll
            for (int off = 1; off < 16; off <<= 1)
#pragma unroll
                for (int r = 0; r < 4; r++) rmax[r] = fmaxf(rmax[r], __shfl_xor(rmax[r], off));

            bool grow = (rmax[0] > mrow[0]) || (rmax[1] > mrow[1]) ||
                        (rmax[2] > mrow[2]) || (rmax[3] > mrow[3]);
            float scl[4] = {1.f, 1.f, 1.f, 1.f};
            const bool doscale = __any(grow);
            if (doscale) {
#pragma unroll
                for (int r = 0; r < 4; r++) {
                    float mn = fmaxf(mrow[r], rmax[r]);
                    scl[r] = exp2f((mrow[r] - mn) * L2E);
                    mrow[r] = mn;
                }
            }
            float rs[4] = {0.f, 0.f, 0.f, 0.f};
#pragma unroll
            for (int st = 0; st < 4; st++) {
#pragma unroll
                for (int r = 0; r < 4; r++) {
                    float p = exp2f((s[st][r] - mrow[r]) * L2E);
                    rs[r] += p;
                    Ph[wid*16*72 + (lg*4 + r)*72 + st*16 + lane16] = (bf16_t)p;
                }
            }
#pragma unroll
            for (int off = 1; off < 16; off <<= 1)
#pragma unroll
                for (int r = 0; r < 4; r++) rs[r] += __shfl_xor(rs[r], off);
            if (doscale) {
#pragma unroll
                for (int r = 0; r < 4; r++) lrow[r] = lrow[r]*scl[r] + rs[r];
#pragma unroll
                for (int nf = 0; nf < 4; nf++)
#pragma unroll
                    for (int r = 0; r < 4; r++) acco[nf][r] *= scl[r];
            } else {
#pragma unroll
                for (int r = 0; r < 4; r++) lrow[r] += rs[r];
            }

            __builtin_amdgcn_s_setprio(1);
#pragma unroll
            for (int ks = 0; ks < 2; ks++) {
                bf16x8 phf = *reinterpret_cast<const bf16x8*>(&Ph[wid*16*72 + lane16*72 + ks*32 + lg*8]);
#pragma unroll
                for (int nf = 0; nf < 4; nf++) {
                    bf16x8 vh = *reinterpret_cast<const bf16x8*>(&Vh[cur][(nf*16 + lane16)*72 + ks*32 + lg*8]);
                    acco[nf] = MFMA16(phf, vh, acco[nf]);
                }
            }
            __builtin_amdgcn_s_setprio(0);

            if (t < qt) WRITE(cur ^ 1);    // stage next tile (loads landed by now)
        }

#pragma unroll
        for (int r = 0; r < 4; r++) {
            float inv = 1.0f / lrow[r];
            int qr = q0 + wid*16 + lg*4 + r;
            size_t base = ((size_t)(b*2048 + qr))*1024 + h*64;
#pragma unroll
            for (int nf = 0; nf < 4; nf++)
                ohi[base + nf*16 + lane16] = (bf16_t)(acco[nf][r] * inv);
        }
    }
}

// ---------------------------------------------------------------------------
extern "C" void kernel_launch(void* const* d_in, const int* in_sizes, int n_in,
                              void* d_out, int out_size, void* d_ws, size_t ws_size,
                              hipStream_t stream)
{
    const float* x  = (const float*)d_in[0];
    const float* Wq = (const float*)d_in[1];
    const float* bq = (const float*)d_in[2];
    const float* Wk = (const float*)d_in[3];
    const float* bk = (const float*)d_in[4];
    const float* Wv = (const float*)d_in[5];
    const float* bv = (const float*)d_in[6];
    const float* Wo = (const float*)d_in[7];
    const float* bo = (const float*)d_in[8];

    char* ws = (char*)d_ws;
    const size_t MB = (size_t)1 << 20;
    bf16_t* xhi    = (bf16_t*)(ws +  0*MB);  // [4096][1024] 8MB
    bf16_t* WThi   = (bf16_t*)(ws +  8*MB);  // [3072][1024] 6MB (Wq|Wk|Wv ^T)
    bf16_t* WoThi  = (bf16_t*)(ws + 14*MB);  // 2MB
    bf16_t* qbuf   = (bf16_t*)(ws + 16*MB);  // [B,H,L,Dh] 8MB
    bf16_t* khibuf = (bf16_t*)(ws + 24*MB);  // 8MB
    bf16_t* vhiT   = (bf16_t*)(ws + 32*MB);  // [B,H,Dh,L] 8MB
    bf16_t* ohibuf = (bf16_t*)(ws + 40*MB);  // [4096][1024] 8MB
    int2*   qwl    = (int2*)  (ws + 48*MB);  // 2MB
    int*    qcnt   = (int*)   (ws + 50*MB);  // 4B
    float*  WqTf   = (float*) (ws + 52*MB);  // [1024][1024] f32 4MB (qfix rows)

    hipMemsetAsync(qcnt, 0, 4, stream);
    k_conv_x<<<4096, 256, 0, stream>>>(x, xhi);
    dim3 tg(32, 32);
    k_transpose<<<tg, 256, 0, stream>>>(Wq, WThi);
    k_transpose<<<tg, 256, 0, stream>>>(Wk, WThi + (size_t)1024*1024);
    k_transpose<<<tg, 256, 0, stream>>>(Wv, WThi + (size_t)2048*1024);
    k_transpose<<<tg, 256, 0, stream>>>(Wo, WoThi);
    k_transpose_f32<<<tg, 256, 0, stream>>>(Wq, WqTf);

    k_gemm3<0><<<768, 256, 0, stream>>>(xhi, WThi, bq, bk, bv,
                                        qbuf, qwl, qcnt, khibuf, vhiT, nullptr);
    k_qfix<<<4096, 64, 0, stream>>>(x, WqTf, bq, qwl, qcnt, qbuf);
    k_attn<<<512, 256, 0, stream>>>(qbuf, khibuf, vhiT, ohibuf);
    k_gemm3<1><<<512, 256, 0, stream>>>(ohibuf, WoThi, bo, nullptr, nullptr,
                                        nullptr, nullptr, nullptr,
                                        nullptr, nullptr, (float*)d_out);
}

// Round 32
// 239.327 us; speedup vs baseline: 1.2112x; 1.0729x over previous
//
#include <hip/hip_runtime.h>
#include <cstddef>
#include <cstdint>
#include <math.h>

typedef __bf16 bf16_t;
typedef __bf16 bf16x8 __attribute__((ext_vector_type(8)));
typedef float  f32x4  __attribute__((ext_vector_type(4)));

#define MFMA16(A,B,C) __builtin_amdgcn_mfma_f32_16x16x32_bf16((A),(B),(C),0,0,0)
#define QFIX_CAP 262144
#define QWIN 2e-3f   // flag window (t-units) = 10 sigma of 1-pass GEMM error

// B=2, L=2048, D=1024, H=16, Dh=64.
// r32 = r31 + attention softmax restructure: group-max (m >= row max is
// sufficient; 4 shfl instead of 16) + lane-local denominator partials
// (per-tile rs reduce eliminated; one final 4-round reduce).  Output
// algebraically identical (m-invariant softmax); smooth rounding shifts
// slightly within budget.

__device__ __forceinline__ void gload16(const bf16_t* g, bf16_t* l)
{
    auto* lp = reinterpret_cast<__attribute__((address_space(3))) uint32_t*>(
                   reinterpret_cast<uintptr_t>(l));
    const auto* gp = reinterpret_cast<const __attribute__((address_space(1))) uint32_t*>(
                   reinterpret_cast<uintptr_t>(g));
    __builtin_amdgcn_global_load_lds(gp, lp, 16, 0, 0);
}

__device__ __forceinline__ void gload4(const float* g, float* l)
{
    auto* lp = reinterpret_cast<__attribute__((address_space(3))) uint32_t*>(
                   reinterpret_cast<uintptr_t>(l));
    const auto* gp = reinterpret_cast<const __attribute__((address_space(1))) uint32_t*>(
                   reinterpret_cast<uintptr_t>(g));
    __builtin_amdgcn_global_load_lds(gp, lp, 4, 0, 0);
}

// ---------------------------------------------------------------------------
__global__ void k_conv_x(const float* __restrict__ x, bf16_t* __restrict__ xhi)
{
    int i = blockIdx.x * blockDim.x + threadIdx.x;
    float4 v = reinterpret_cast<const float4*>(x)[i];
    bf16_t* ph = xhi + 4*(size_t)i;
    ph[0]=(bf16_t)v.x; ph[1]=(bf16_t)v.y; ph[2]=(bf16_t)v.z; ph[3]=(bf16_t)v.w;
}

// W f32 [k][n] (1024x1024) -> T[n][k] bf16
__global__ void k_transpose(const float* __restrict__ W, bf16_t* __restrict__ T)
{
    __shared__ float tile[32][33];
    int t = threadIdx.x, r = t >> 5, c = t & 31;
    int k0 = blockIdx.y * 32, n0 = blockIdx.x * 32;
#pragma unroll
    for (int i = 0; i < 4; i++)
        tile[r + i*8][c] = W[(size_t)(k0 + r + i*8) * 1024 + n0 + c];
    __syncthreads();
#pragma unroll
    for (int i = 0; i < 4; i++) {
        int nr = r + i*8;
        T[(size_t)(n0 + nr) * 1024 + k0 + c] = (bf16_t)tile[c][nr];
    }
}

// W f32 [k][n] -> T f32 [n][k]  (for the exact qfix row reads)
__global__ void k_transpose_f32(const float* __restrict__ W, float* __restrict__ T)
{
    __shared__ float tile[32][33];
    int t = threadIdx.x, r = t >> 5, c = t & 31;
    int k0 = blockIdx.y * 32, n0 = blockIdx.x * 32;
#pragma unroll
    for (int i = 0; i < 4; i++)
        tile[r + i*8][c] = W[(size_t)(k0 + r + i*8) * 1024 + n0 + c];
    __syncthreads();
#pragma unroll
    for (int i = 0; i < 4; i++) {
        int nr = r + i*8;
        T[(size_t)(n0 + nr) * 1024 + k0 + c] = tile[c][nr];
    }
}

// ---------------------------------------------------------------------------
// Single-pass bf16 MFMA GEMM, depth-2 prefetch, 3 LDS buffers, XCD-local B.
// MODE 0 (QKV): 128x128 tile, N=3072. Epilogue: Q floor+flag(QWIN) / K / V^T.
// MODE 1 (out-proj): 64x128 tile, N=1024 -> f32 d_out + bo.
template<int MODE>
__launch_bounds__(256)
__global__ void k_gemm3(const bf16_t* __restrict__ A, const bf16_t* __restrict__ Bt,
                        const float* __restrict__ b0, const float* __restrict__ b1,
                        const float* __restrict__ b2,
                        bf16_t* __restrict__ qout, int2* __restrict__ qwl,
                        int* __restrict__ qcnt,
                        bf16_t* __restrict__ kho, bf16_t* __restrict__ vho,
                        float* __restrict__ fout)
{
    constexpr int BM = (MODE == 0) ? 128 : 64;
    __shared__ bf16_t As[3][BM*32]  __attribute__((aligned(16)));
    __shared__ bf16_t Bs[3][128*32] __attribute__((aligned(16)));

    const int bid = blockIdx.x;
    const int xcd = bid & 7;
    const int i   = bid >> 3;
    int n0, m0;
    if constexpr (MODE == 0) {
        n0 = (xcd * 3 + (i % 3)) * 128;   // each XCD owns 3 n-tiles (L2-resident B)
        m0 = (i / 3) * 128;
    } else {
        n0 = xcd * 128;
        m0 = i * 64;
    }

    const int tid = threadIdx.x;
    const int wid = tid >> 6, lane = tid & 63, lane16 = lane & 15, lg = lane >> 4;
    constexpr int WM = (MODE == 0) ? 64 : 32;
    const int wm = (wid >> 1) * WM, wn = (wid & 1) * 64;
    constexpr int MI = (MODE == 0) ? 4 : 2;

    f32x4 acc[MI][4] = {};

    auto STAGE = [&](int buf, int kt) {
        const int k0 = kt * 32;
#pragma unroll
        for (int i2 = 0; i2 < BM/64; i2++) {
            const int c = tid + i2*256;
            const int row = c >> 2, col = (c & 3) * 8;
            gload16(&A[(size_t)(m0 + row) * 1024 + k0 + col], &As[buf][c*8]);
        }
#pragma unroll
        for (int i2 = 0; i2 < 2; i2++) {
            const int c = tid + i2*256;
            const int row = c >> 2, col = (c & 3) * 8;
            gload16(&Bt[(size_t)(n0 + row) * 1024 + k0 + col], &Bs[buf][c*8]);
        }
    };

    STAGE(0, 0);
    STAGE(1, 1);
    for (int kt = 0; kt < 32; ++kt) {
        const int cur = kt % 3;
        if (kt < 31) {
            if constexpr (MODE == 0) { asm volatile("s_waitcnt vmcnt(4)" ::: "memory"); }
            else                     { asm volatile("s_waitcnt vmcnt(3)" ::: "memory"); }
        } else asm volatile("s_waitcnt vmcnt(0)" ::: "memory");
        __builtin_amdgcn_s_barrier();

        bf16x8 a[MI], b[4];
#pragma unroll
        for (int ii = 0; ii < MI; ii++)
            a[ii] = *reinterpret_cast<const bf16x8*>(&As[cur][(wm + ii*16 + lane16)*32 + lg*8]);
#pragma unroll
        for (int j = 0; j < 4; j++)
            b[j] = *reinterpret_cast<const bf16x8*>(&Bs[cur][(wn + j*16 + lane16)*32 + lg*8]);
#pragma unroll
        for (int ii = 0; ii < MI; ii++)
#pragma unroll
            for (int j = 0; j < 4; j++)
                acc[ii][j] = MFMA16(a[ii], b[j], acc[ii][j]);

        if (kt + 2 < 32) STAGE((kt + 2) % 3, kt + 2);
    }

    if constexpr (MODE == 1) {
#pragma unroll
        for (int j = 0; j < 4; j++) {
            const int n = n0 + wn + j*16 + lane16;
#pragma unroll
            for (int ii = 0; ii < MI; ii++)
#pragma unroll
                for (int r = 0; r < 4; r++) {
                    const int m = m0 + wm + ii*16 + lg*4 + r;
                    fout[(size_t)m*1024 + n] = acc[ii][j][r] + b0[n];
                }
        }
    } else if (n0 >= 1024) {
#pragma unroll
        for (int j = 0; j < 4; j++) {
            const int n = n0 + wn + j*16 + lane16;
#pragma unroll
            for (int ii = 0; ii < MI; ii++)
#pragma unroll
                for (int r = 0; r < 4; r++) {
                    const int m = m0 + wm + ii*16 + lg*4 + r;
                    const int bb = m >> 11, l = m & 2047;
                    float v = acc[ii][j][r];
                    if (n < 2048) {
                        const int nk = n - 1024;
                        kho[(((size_t)(bb*16 + (nk>>6)))*2048 + l)*64 + (nk&63)] =
                            (bf16_t)(v + b1[nk]);
                    } else {
                        const int nv = n - 2048;
                        vho[(((size_t)(bb*16 + (nv>>6)))*64 + (nv&63))*2048 + l] =
                            (bf16_t)(v + b2[nv]);
                    }
                }
        }
    } else {
        // Q epilogue: floors + wave-aggregated flag append (1 atomic/wave)
        int cnt = 0;
#pragma unroll
        for (int j = 0; j < 4; j++) {
            const int n = n0 + wn + j*16 + lane16;
            const float bias = b0[n];
#pragma unroll
            for (int ii = 0; ii < MI; ii++)
#pragma unroll
                for (int r = 0; r < 4; r++) {
                    const int m = m0 + wm + ii*16 + lg*4 + r;
                    const int bb = m >> 11, l = m & 2047;
                    float t  = (acc[ii][j][r] + bias) * 0.125f;
                    float fl = floorf(t);
                    float fr = t - fl;
                    cnt += (fr < QWIN || fr > 1.0f - QWIN) ? 1 : 0;
                    qout[(((size_t)(bb*16 + (n>>6)))*2048 + l)*64 + (n&63)] = (bf16_t)fl;
                }
        }
        int pre = cnt;
#pragma unroll
        for (int off = 1; off < 64; off <<= 1) {
            int t2 = __shfl_up(pre, off);
            if (lane >= off) pre += t2;
        }
        int total = __shfl(pre, 63);
        int base = 0;
        if (lane == 63 && total > 0) base = atomicAdd(qcnt, total);
        base = __shfl(base, 63);
        int idx = base + pre - cnt;
#pragma unroll
        for (int j = 0; j < 4; j++) {
            const int n = n0 + wn + j*16 + lane16;
            const float bias = b0[n];
#pragma unroll
            for (int ii = 0; ii < MI; ii++)
#pragma unroll
                for (int r = 0; r < 4; r++) {
                    const int m = m0 + wm + ii*16 + lg*4 + r;
                    float t  = (acc[ii][j][r] + bias) * 0.125f;
                    float fr = t - floorf(t);
                    if (fr < QWIN || fr > 1.0f - QWIN) {
                        if (idx < QFIX_CAP) qwl[idx] = make_int2(m, n);
                        idx++;
                    }
                }
        }
    }
}

// ---------------------------------------------------------------------------
// Wave-cooperative exact fixup, async-DMA staged: 1 wave per 64 elements.
__launch_bounds__(64)
__global__ void k_qfix(const float* __restrict__ x, const float* __restrict__ WqT,
                       const float* __restrict__ bq, const int2* __restrict__ wl,
                       const int* __restrict__ count, bf16_t* __restrict__ qout)
{
    __shared__ float xs [64][65];
    __shared__ float wsd[64][65];
    int cnt = *count; if (cnt > QFIX_CAP) cnt = QFIX_CAP;
    const int base = blockIdx.x * 64;
    if (base >= cnt) return;
    const int lane = threadIdx.x;
    const int i = base + lane;
    const bool act = (i < cnt);
    const int2 e = wl[act ? i : base];
    const int m = e.x, n = e.y;

    float r0 = 0.f, r1 = 0.f;
#pragma unroll 1
    for (int c = 0; c < 16; ++c) {
        const int d0 = c * 64;
#pragma unroll 8
        for (int s = 0; s < 64; ++s) {
            int ms = __shfl(m, s);
            int ns = __shfl(n, s);
            gload4(&x  [(size_t)ms * 1024 + d0 + lane], &xs [s][0]);   // DMA, 256B row
            gload4(&WqT[(size_t)ns * 1024 + d0 + lane], &wsd[s][0]);   // DMA, 256B row
        }
        asm volatile("s_waitcnt vmcnt(0)" ::: "memory");   // all DMAs landed
        float racc = (c < 8) ? r0 : r1;
#pragma unroll
        for (int d = 0; d < 64; ++d)
            racc = fmaf(xs[lane][d], wsd[lane][d], racc);  // ascending-d chain
        if (c < 8) r0 = racc; else r1 = racc;
        asm volatile("s_waitcnt lgkmcnt(0)" ::: "memory"); // reads done before next DMA (WAR)
    }
    if (act) {
        float acc = __fadd_rn(r0, r1);                     // KC=512 block merge
        float q = floorf(__fmul_rn(__fadd_rn(acc, bq[n]), 0.125f));
        qout[(((size_t)((m>>11)*16 + (n>>6)))*2048 + (m&2047))*64 + (n&63)] = (bf16_t)q;
    }
}

// ---------------------------------------------------------------------------
// Flash attention, bf16 K/V/P.  Flat grid 512: xcd = bid&7 owns 4 heads;
// block handles q-tiles {bx, 31-bx}.  T14 pipeline; group-max softmax with
// lane-local denominator partials (final cross-lane reduce once).
__launch_bounds__(256)
__global__ void k_attn(const bf16_t* __restrict__ qf,
                       const bf16_t* __restrict__ khi,
                       const bf16_t* __restrict__ vhiT,
                       bf16_t* __restrict__ ohi)
{
    __shared__ bf16_t Kh[2][64*72] __attribute__((aligned(16)));
    __shared__ bf16_t Vh[2][64*72] __attribute__((aligned(16)));
    __shared__ bf16_t Ph[4*16*72]  __attribute__((aligned(16)));
    const int tid = threadIdx.x, wid = tid >> 6, lane = tid & 63;
    const int lane16 = lane & 15, lg = lane >> 4;
    const int bid = blockIdx.x;
    const int xcd = bid & 7;
    const int ib  = bid >> 3;            // 0..63
    const int bh  = xcd * 4 + (ib & 3);  // 4 heads per XCD -> K/V L2-resident
    const int bx  = ib >> 2;             // 0..15
    const bf16_t* qb  = qf   + (size_t)bh * 2048 * 64;
    const bf16_t* khb = khi  + (size_t)bh * 2048 * 64;
    const bf16_t* vhb = vhiT + (size_t)bh * 64 * 2048;
    const int b = bh >> 4, h = bh & 15;
    const float L2E = 1.44269504088896f;

    bf16x8 kreg[2], vreg[2];
    auto ISSUE = [&](int t) {
        const int kv0 = t * 64;
#pragma unroll
        for (int i = 0; i < 2; i++) {
            int cc = tid + i*256, row = cc >> 3, col8 = (cc & 7) * 8;
            kreg[i] = *reinterpret_cast<const bf16x8*>(&khb[(size_t)(kv0+row)*64 + col8]);
            vreg[i] = *reinterpret_cast<const bf16x8*>(&vhb[(size_t)row*2048 + kv0 + col8]);
        }
    };
    auto WRITE = [&](int buf) {
#pragma unroll
        for (int i = 0; i < 2; i++) {
            int cc = tid + i*256, row = cc >> 3, col8 = (cc & 7) * 8;
            *reinterpret_cast<bf16x8*>(&Kh[buf][row*72 + col8]) = kreg[i];
            *reinterpret_cast<bf16x8*>(&Vh[buf][row*72 + col8]) = vreg[i];
        }
    };

#pragma unroll 1
    for (int pass = 0; pass < 2; pass++) {
        const int qt = pass ? (31 - bx) : bx;
        const int q0 = qt * 64;
        const int qrow16 = q0 + wid*16 + lane16;

        bf16x8 qfr0 = *reinterpret_cast<const bf16x8*>(&qb[(size_t)qrow16*64 + lg*8]);
        bf16x8 qfr1 = *reinterpret_cast<const bf16x8*>(&qb[(size_t)qrow16*64 + 32 + lg*8]);

        f32x4 acco[4] = {};
        float mrow = -1e30f;                 // group max (shared across 4 rows)
        float lrow[4] = {0.f, 0.f, 0.f, 0.f};  // lane-local denominator partials

        __syncthreads();            // prior pass readers done before buf0 reuse
        ISSUE(0);
        WRITE(0);

        for (int t = 0; t <= qt; t++) {
            const int cur = t & 1;
            if (t < qt) ISSUE(t + 1);      // in flight during compute
            __syncthreads();               // buf[cur] visible; old buf free

            f32x4 s[4] = {};
            __builtin_amdgcn_s_setprio(1);
#pragma unroll
            for (int st = 0; st < 4; st++) {
                const int ro = (st*16 + lane16)*72;
                bf16x8 kh0 = *reinterpret_cast<const bf16x8*>(&Kh[cur][ro + lg*8]);
                bf16x8 kh1 = *reinterpret_cast<const bf16x8*>(&Kh[cur][ro + 32 + lg*8]);
                s[st] = MFMA16(qfr0, kh0, s[st]);
                s[st] = MFMA16(qfr1, kh1, s[st]);
            }
            __builtin_amdgcn_s_setprio(0);
            if (t == qt) {
#pragma unroll
                for (int st = 0; st < 4; st++) {
                    int key = t*64 + st*16 + lane16;
#pragma unroll
                    for (int r = 0; r < 4; r++) {
                        int qr = q0 + wid*16 + lg*4 + r;
                        if (key > qr) s[st][r] = -1e30f;
                    }
                }
            }
            // group max: over st,r locally (15 fmax), then 4-round shfl
            float gm = s[0][0];
#pragma unroll
            for (int st = 0; st < 4; st++)
#pragma unroll
                for (int r = 0; r < 4; r++) gm = fmaxf(gm, s[st][r]);
#pragma unroll
            for (int off = 1; off < 16; off <<= 1)
                gm = fmaxf(gm, __shfl_xor(gm, off));

            if (__any(gm > mrow)) {
                float mn = fmaxf(mrow, gm);
                float scl = exp2f((mrow - mn) * L2E);   // ==1.0 exactly if no growth
                mrow = mn;
#pragma unroll
                for (int r = 0; r < 4; r++) lrow[r] *= scl;
#pragma unroll
                for (int nf = 0; nf < 4; nf++)
#pragma unroll
                    for (int r = 0; r < 4; r++) acco[nf][r] *= scl;
            }
#pragma unroll
            for (int st = 0; st < 4; st++) {
#pragma unroll
                for (int r = 0; r < 4; r++) {
                    float p = exp2f((s[st][r] - mrow) * L2E);
                    lrow[r] += p;                        // lane-local partial
                    Ph[wid*16*72 + (lg*4 + r)*72 + st*16 + lane16] = (bf16_t)p;
                }
            }

            __builtin_amdgcn_s_setprio(1);
#pragma unroll
            for (int ks = 0; ks < 2; ks++) {
                bf16x8 phf = *reinterpret_cast<const bf16x8*>(&Ph[wid*16*72 + lane16*72 + ks*32 + lg*8]);
#pragma unroll
                for (int nf = 0; nf < 4; nf++) {
                    bf16x8 vh = *reinterpret_cast<const bf16x8*>(&Vh[cur][(nf*16 + lane16)*72 + ks*32 + lg*8]);
                    acco[nf] = MFMA16(phf, vh, acco[nf]);
                }
            }
            __builtin_amdgcn_s_setprio(0);

            if (t < qt) WRITE(cur ^ 1);    // stage next tile (loads landed by now)
        }

        // final denominator reduce (once per pass)
#pragma unroll
        for (int off = 1; off < 16; off <<= 1)
#pragma unroll
            for (int r = 0; r < 4; r++) lrow[r] += __shfl_xor(lrow[r], off);

#pragma unroll
        for (int r = 0; r < 4; r++) {
            float inv = 1.0f / lrow[r];
            int qr = q0 + wid*16 + lg*4 + r;
            size_t base = ((size_t)(b*2048 + qr))*1024 + h*64;
#pragma unroll
            for (int nf = 0; nf < 4; nf++)
                ohi[base + nf*16 + lane16] = (bf16_t)(acco[nf][r] * inv);
        }
    }
}

// ---------------------------------------------------------------------------
extern "C" void kernel_launch(void* const* d_in, const int* in_sizes, int n_in,
                              void* d_out, int out_size, void* d_ws, size_t ws_size,
                              hipStream_t stream)
{
    const float* x  = (const float*)d_in[0];
    const float* Wq = (const float*)d_in[1];
    const float* bq = (const float*)d_in[2];
    const float* Wk = (const float*)d_in[3];
    const float* bk = (const float*)d_in[4];
    const float* Wv = (const float*)d_in[5];
    const float* bv = (const float*)d_in[6];
    const float* Wo = (const float*)d_in[7];
    const float* bo = (const float*)d_in[8];

    char* ws = (char*)d_ws;
    const size_t MB = (size_t)1 << 20;
    bf16_t* xhi    = (bf16_t*)(ws +  0*MB);  // [4096][1024] 8MB
    bf16_t* WThi   = (bf16_t*)(ws +  8*MB);  // [3072][1024] 6MB (Wq|Wk|Wv ^T)
    bf16_t* WoThi  = (bf16_t*)(ws + 14*MB);  // 2MB
    bf16_t* qbuf   = (bf16_t*)(ws + 16*MB);  // [B,H,L,Dh] 8MB
    bf16_t* khibuf = (bf16_t*)(ws + 24*MB);  // 8MB
    bf16_t* vhiT   = (bf16_t*)(ws + 32*MB);  // [B,H,Dh,L] 8MB
    bf16_t* ohibuf = (bf16_t*)(ws + 40*MB);  // [4096][1024] 8MB
    int2*   qwl    = (int2*)  (ws + 48*MB);  // 2MB
    int*    qcnt   = (int*)   (ws + 50*MB);  // 4B
    float*  WqTf   = (float*) (ws + 52*MB);  // [1024][1024] f32 4MB (qfix rows)

    hipMemsetAsync(qcnt, 0, 4, stream);
    k_conv_x<<<4096, 256, 0, stream>>>(x, xhi);
    dim3 tg(32, 32);
    k_transpose<<<tg, 256, 0, stream>>>(Wq, WThi);
    k_transpose<<<tg, 256, 0, stream>>>(Wk, WThi + (size_t)1024*1024);
    k_transpose<<<tg, 256, 0, stream>>>(Wv, WThi + (size_t)2048*1024);
    k_transpose<<<tg, 256, 0, stream>>>(Wo, WoThi);
    k_transpose_f32<<<tg, 256, 0, stream>>>(Wq, WqTf);

    k_gemm3<0><<<768, 256, 0, stream>>>(xhi, WThi, bq, bk, bv,
                                        qbuf, qwl, qcnt, khibuf, vhiT, nullptr);
    k_qfix<<<4096, 64, 0, stream>>>(x, WqTf, bq, qwl, qcnt, qbuf);
    k_attn<<<512, 256, 0, stream>>>(qbuf, khibuf, vhiT, ohibuf);
    k_gemm3<1><<<512, 256, 0, stream>>>(ohibuf, WoThi, bo, nullptr, nullptr,
                                        nullptr, nullptr, nullptr,
                                        nullptr, nullptr, (float*)d_out);
}